// Round 8
// baseline (180.040 us; speedup 1.0000x reference)
//
#include <hip/hip_runtime.h>

#define BATCH 4096
#define D_IN 1024
#define D_OUT 1024
#define N_EXPERTS 8

#define TK 32
#define MAX_TILES 71        // TM=64 list bound (fallback)
#define MAX_TILES_128 39    // TM=128: 32 + 7

// ws int32 region (slots)
#define WS_PERM    0       // [4096]
#define WS_STARTS  4096    // [9]
#define WS_TILE_E  4112    // [160]
#define WS_TILE_M  4280    // [160]
#define WS_NTILES  4448    // [1]

// staged bf16 regions (byte offsets into ws)
#define WS_XHI_OFF   32768
#define WS_XLO_OFF   (32768 + 8388608)
#define WS_WHI_OFF   (32768 + 2*8388608)
#define WS_WLO_OFF   (32768 + 2*8388608 + 16777216)
#define WS_NEEDED    (32768 + 2*8388608 + 2*16777216)   // 50,364,416 B

typedef __attribute__((ext_vector_type(8))) short short8;   // 8 x bf16
typedef __attribute__((ext_vector_type(4))) float f32x4;

// fp32 -> bf16 hi/lo split (truncation; lo = next 8 mantissa bits). Unchanged.
__device__ __forceinline__ void cvt8(const float4 a, const float4 b,
                                     short8& h, short8& l) {
    float f[8] = {a.x, a.y, a.z, a.w, b.x, b.y, b.z, b.w};
#pragma unroll
    for (int i = 0; i < 8; ++i) {
        const unsigned u = __float_as_uint(f[i]);
        h[i] = (short)(u >> 16);
        const float r = f[i] - __uint_as_float(u & 0xffff0000u);
        l[i] = (short)(__float_as_uint(r) >> 16);
    }
}

// ---------------------------------------------------------------------------
// Fused prep kernel (validated R3-R7). tm_tile = 128 (pc) / 64 (fallback).
// ---------------------------------------------------------------------------
__global__ __launch_bounds__(256) void prep_kernel(
    const int* __restrict__ actions, const int* __restrict__ mxs,
    const float* __restrict__ xs, const float* __restrict__ W,
    int* __restrict__ ws,
    short* __restrict__ XhiP, short* __restrict__ XloP,
    short* __restrict__ WhiP, short* __restrict__ WloP,
    float* __restrict__ out, int meta_mode, int tm_tile)
{
    const int bid = blockIdx.x;
    const int t = threadIdx.x;

    if (bid == 0) {
        __shared__ int chunkoff[64][N_EXPERTS];
        const int lane = t & 63;
        const int wave = t >> 6;

        for (int it = 0; it < 16; ++it) {
            const int c = wave * 16 + it;
            const int a = actions[c * 64 + lane];
            int myc = 0;
#pragma unroll
            for (int e = 0; e < N_EXPERTS; ++e) {
                const unsigned long long me = __ballot(a == e);
                if (lane == e) myc = (int)__popcll(me);
            }
            if (lane < N_EXPERTS) chunkoff[c][lane] = myc;
        }
        __syncthreads();

        if (wave == 0) {
            int cc0 = chunkoff[lane][0], cc1 = chunkoff[lane][1];
            int cc2 = chunkoff[lane][2], cc3 = chunkoff[lane][3];
            int cc4 = chunkoff[lane][4], cc5 = chunkoff[lane][5];
            int cc6 = chunkoff[lane][6], cc7 = chunkoff[lane][7];
            int tot0, tot1, tot2, tot3, tot4, tot5, tot6, tot7;
            int ex0, ex1, ex2, ex3, ex4, ex5, ex6, ex7;
#define SCAN1(CC, TOT, EX) do {                                   \
            int v = CC;                                           \
            _Pragma("unroll")                                     \
            for (int d = 1; d < 64; d <<= 1) {                    \
                const int u = __shfl_up(v, d, 64);                \
                if (lane >= d) v += u;                            \
            }                                                     \
            TOT = __shfl(v, 63, 64);                              \
            EX = v - CC;                                          \
        } while (0)
            SCAN1(cc0, tot0, ex0); SCAN1(cc1, tot1, ex1);
            SCAN1(cc2, tot2, ex2); SCAN1(cc3, tot3, ex3);
            SCAN1(cc4, tot4, ex4); SCAN1(cc5, tot5, ex5);
            SCAN1(cc6, tot6, ex6); SCAN1(cc7, tot7, ex7);
#undef SCAN1
            const int b0 = 0;
            const int b1 = b0 + tot0, b2 = b1 + tot1, b3 = b2 + tot2;
            const int b4 = b3 + tot3, b5 = b4 + tot4, b6 = b5 + tot5;
            const int b7 = b6 + tot6;
            chunkoff[lane][0] = b0 + ex0; chunkoff[lane][1] = b1 + ex1;
            chunkoff[lane][2] = b2 + ex2; chunkoff[lane][3] = b3 + ex3;
            chunkoff[lane][4] = b4 + ex4; chunkoff[lane][5] = b5 + ex5;
            chunkoff[lane][6] = b6 + ex6; chunkoff[lane][7] = b7 + ex7;
            if (lane == 0) {
                ws[WS_STARTS + 0] = b0; ws[WS_STARTS + 1] = b1;
                ws[WS_STARTS + 2] = b2; ws[WS_STARTS + 3] = b3;
                ws[WS_STARTS + 4] = b4; ws[WS_STARTS + 5] = b5;
                ws[WS_STARTS + 6] = b6; ws[WS_STARTS + 7] = b7;
                ws[WS_STARTS + 8] = BATCH;
                int nt = 0;
                int tots[8] = {tot0, tot1, tot2, tot3, tot4, tot5, tot6, tot7};
#pragma unroll
                for (int e = 0; e < N_EXPERTS; ++e)
                    for (int m0 = 0; m0 < tots[e]; m0 += tm_tile) {
                        ws[WS_TILE_E + nt] = e;
                        ws[WS_TILE_M + nt] = m0;
                        ++nt;
                    }
                ws[WS_NTILES] = nt;
            }
        }
        __syncthreads();

        for (int it = 0; it < 16; ++it) {
            const int c = wave * 16 + it;
            const int i = c * 64 + lane;
            const int a = actions[i];
            unsigned long long msel = 0;
#pragma unroll
            for (int e = 0; e < N_EXPERTS; ++e) {
                const unsigned long long me = __ballot(a == e);
                if (a == e) msel = me;
            }
            const int rank = (int)__popcll(msel & ((1ull << lane) - 1ull));
            const int pos = chunkoff[c][a] + rank;
            ws[WS_PERM + pos] = i;
        }
        return;
    }

    if (bid <= 16) {
        const int i = (bid - 1) * 256 + t;
        if (meta_mode == 2) {
            out[BATCH * D_OUT + i] = (float)mxs[i];
            long long* a64 = (long long*)(out + BATCH * D_OUT + BATCH);
            a64[i] = (long long)actions[i];
        } else if (meta_mode == 1) {
            out[BATCH * D_OUT + i] = (float)mxs[i];
            out[BATCH * D_OUT + BATCH + i] = (float)actions[i];
        }
        return;
    }

    const int g = (bid - 17) * 256 + t;
    if (g < 1048576) {
        // g = (((e*32+kt)*8+nt)*8 + i2)*64 + slot ; slot = j*16 + c
        const int slot = g & 63;
        const int i2   = (g >> 6) & 7;
        const int blk  = g >> 9;
        const int nt   = blk & 7;
        const int kt   = (blk >> 3) & 31;
        const int e    = blk >> 8;
        const int c    = slot & 15;
        const int j    = slot >> 4;
        const int n    = nt * 128 + i2 * 16 + c;
        const float* p = W + ((size_t)(e << 10) + n) * D_IN + kt * 32 + j * 8;
        const float4 f0 = *(const float4*)p;
        const float4 f1 = *(const float4*)(p + 4);
        short8 h, l;
        cvt8(f0, f1, h, l);
        *(short8*)(WhiP + (size_t)g * 8) = h;
        *(short8*)(WloP + (size_t)g * 8) = l;
    } else {
        const int g2 = g - 1048576;   // < 524288
        const float* p = xs + (size_t)g2 * 8;
        const float4 f0 = *(const float4*)p;
        const float4 f1 = *(const float4*)(p + 4);
        short8 h, l;
        cvt8(f0, f1, h, l);
        *(short8*)(XhiP + (size_t)g2 * 8) = h;
        *(short8*)(XloP + (size_t)g2 * 8) = l;
    }
}

// ---------------------------------------------------------------------------
// R8 GEMM: 128x128 tile, 8 waves. B-only LDS (4 bufs x 16KB = 64KB ->
// 2 blocks/CU, one round) with depth-3 counted-vmcnt DMA; A fragments in
// registers (2 named sets X/Y) with asm(""::: "memory") fences pinning
// issue order [A-loads -> DMA -> wait] so the in-order vmcnt arithmetic
// is exact (R7's failure: unpinned loads got sunk to use, depth -> 0).
// Steady phase: ALOAD(t+1); fence; STAGE(t+3); vmcnt(8)+barrier
// [completes A(t), S(t+1..t) per in-order; leaves S(t+2)2+A(t+1)4+S(t+3)2];
// 8 ds_read; lgkm(0)+barrier+sched_barrier; 24 MFMA.
// A window = 1 phase (L2-hit: XCD m-colocation remap keeps a tile's 8
// nsl-blocks on one XCD); B window = 2-3 phases >> HBM latency.
// ---------------------------------------------------------------------------
#define TM5 128
#define TN5 128

__global__ __launch_bounds__(512, 4) void moe_gemm_pc(
    const short* __restrict__ Xhi, const short* __restrict__ Xlo,
    const short* __restrict__ Whi, const short* __restrict__ Wlo,
    const float* __restrict__ bias, const int* __restrict__ ws,
    float* __restrict__ out)
{
    const int wid = blockIdx.x;
    const int xcd = wid & 7;
    const int j5  = wid >> 3;
    const int nsl = j5 & 7;
    const int tix = (j5 >> 3) * 8 + xcd;
    if (tix >= ws[WS_NTILES]) return;
    const int e   = ws[WS_TILE_E + tix];
    const int m0  = ws[WS_TILE_M + tix];
    const int s0  = ws[WS_STARTS + e];
    const int cnt = ws[WS_STARTS + e + 1] - s0;
    const int n0  = nsl * TN5;

    __shared__ short Bhi[4][8 * 512];   // [buf][frag-tile(8)][slot(64)][8]
    __shared__ short Blo[4][8 * 512];
    __shared__ int   rows_s[TM5];

    const int t = threadIdx.x;
    if (t < TM5) {
        const int r = m0 + t;
        rows_s[t] = (r < cnt) ? ws[WS_PERM + s0 + r] : -1;
    }
    __syncthreads();

    const int lane = t & 63;
    const int wave = t >> 6;          // 0..7
    const int wm = (wave >> 1) * 32;  // quadrant m base (0,32,64,96)
    const int wn = (wave & 1) * 64;   // quadrant n base (0,64)

    const float zf = 0.f;
    f32x4 acc[2][4];
#pragma unroll
    for (int mi = 0; mi < 2; ++mi)
#pragma unroll
        for (int nj = 0; nj < 4; ++nj)
            acc[mi][nj] = (f32x4){zf, zf, zf, zf};

    // A reg sources (validated R7 mapping): lane l -> row rows_s[wm+mi*16+(l&15)],
    // k-octet l>>4. Pad rows clamp to 0 (acc garbage, never stored).
    const int fr = lane & 15;
    const int jo = lane >> 4;
    int r0 = rows_s[wm + fr];       if (r0 < 0) r0 = 0;
    int r1 = rows_s[wm + 16 + fr];  if (r1 < 0) r1 = 0;
    const short* aH0 = Xhi + (size_t)r0 * D_IN + jo * 8;
    const short* aH1 = Xhi + (size_t)r1 * D_IN + jo * 8;
    const short* aL0 = Xlo + (size_t)r0 * D_IN + jo * 8;
    const short* aL1 = Xlo + (size_t)r1 * D_IN + jo * 8;

    // B staging: staged block ((e*32+kt)*8+nsl)*4096 shorts; wave w stages
    // frag tile w (hi + lo, 1KB each -> 2 DMA/wave/K-step; 16/block).
    const size_t wBase = ((size_t)e * 256 + (size_t)nsl) * 4096;
    const size_t bo = (size_t)wave * 512 + lane * 8;

    // Two named A register sets (rule #20).
    short8 Xh0, Xh1, Xl0, Xl1, Yh0, Yh1, Yl0, Yl1;

#define ALOAD(P, KT) do {                                                     \
        const int _o = (KT) * 32;                                             \
        P##h0 = *(const short8*)(aH0 + _o);                                   \
        P##h1 = *(const short8*)(aH1 + _o);                                   \
        P##l0 = *(const short8*)(aL0 + _o);                                   \
        P##l1 = *(const short8*)(aL1 + _o);                                   \
    } while (0)

    // compiler-level fence: pins A-loads before the following DMAs (keeps
    // the in-order vmcnt arithmetic exact). No instruction emitted.
#define AFENCE() asm volatile("" ::: "memory")

#define STAGE(KT, BUF) do {                                                    \
        const size_t _wo = wBase + (size_t)(KT) * 32768;                       \
        __builtin_amdgcn_global_load_lds(                                      \
            (const __attribute__((address_space(1))) void*)(Whi + _wo + bo),   \
            (__attribute__((address_space(3))) void*)&Bhi[BUF][wave * 512],    \
            16, 0, 0);                                                         \
        __builtin_amdgcn_global_load_lds(                                      \
            (const __attribute__((address_space(1))) void*)(Wlo + _wo + bo),   \
            (__attribute__((address_space(3))) void*)&Blo[BUF][wave * 512],    \
            16, 0, 0);                                                         \
    } while (0)

#define WAITB(N) asm volatile("s_waitcnt vmcnt(" #N ")\n\ts_barrier" ::: "memory")

    const int rds = lane * 8;   // linear fragment read, conflict-free

    // ds_read B frags -> lgkm(0)+barrier (frees this buf for the DMA that
    // targets it next iter) -> sched_barrier (rule #18: pin MFMA below) ->
    // 24 MFMA from registers.
#define COMPUTE(BUF, P) do {                                                 \
        short8 bh[4], bl[4];                                                 \
        _Pragma("unroll")                                                    \
        for (int i2 = 0; i2 < 4; ++i2) {                                     \
            const int boff = ((wn >> 4) + i2) * 512 + rds;                   \
            bh[i2] = *(const short8*)&Bhi[BUF][boff];                        \
            bl[i2] = *(const short8*)&Blo[BUF][boff];                        \
        }                                                                    \
        asm volatile("s_waitcnt lgkmcnt(0)\n\ts_barrier" ::: "memory");      \
        __builtin_amdgcn_sched_barrier(0);                                   \
        _Pragma("unroll")                                                    \
        for (int nj = 0; nj < 4; ++nj) {                                     \
            acc[0][nj] = __builtin_amdgcn_mfma_f32_16x16x32_bf16(P##h0, bh[nj], acc[0][nj], 0, 0, 0); \
            acc[0][nj] = __builtin_amdgcn_mfma_f32_16x16x32_bf16(P##h0, bl[nj], acc[0][nj], 0, 0, 0); \
            acc[0][nj] = __builtin_amdgcn_mfma_f32_16x16x32_bf16(P##l0, bh[nj], acc[0][nj], 0, 0, 0); \
            acc[1][nj] = __builtin_amdgcn_mfma_f32_16x16x32_bf16(P##h1, bh[nj], acc[1][nj], 0, 0, 0); \
            acc[1][nj] = __builtin_amdgcn_mfma_f32_16x16x32_bf16(P##h1, bl[nj], acc[1][nj], 0, 0, 0); \
            acc[1][nj] = __builtin_amdgcn_mfma_f32_16x16x32_bf16(P##l1, bh[nj], acc[1][nj], 0, 0, 0); \
        }                                                                    \
    } while (0)

    // ---- prologue: A(0) -> X; stage tiles 0,1,2 ----
    ALOAD(X, 0);
    AFENCE();
    STAGE(0, 0); STAGE(1, 1); STAGE(2, 2);
    // ---- k=0 (peeled) ----
    ALOAD(Y, 1);
    AFENCE();
    STAGE(3, 3);
    WAITB(6);              // A(0)+S(0..2) done; in flight A(1)4+S(3)2
    COMPUTE(0, X);

    // ---- main: k = 1..28, unroll-4 (static bufs/sets) ----
#pragma unroll 1
    for (int i = 0; i < 7; ++i) {
        const int k = 1 + 4 * i;
        ALOAD(X, k + 1); AFENCE(); STAGE(k + 3, 0); WAITB(8); COMPUTE(1, Y);
        ALOAD(Y, k + 2); AFENCE(); STAGE(k + 4, 1); WAITB(8); COMPUTE(2, X);
        ALOAD(X, k + 3); AFENCE(); STAGE(k + 5, 2); WAITB(8); COMPUTE(3, Y);
        ALOAD(Y, k + 4); AFENCE(); STAGE(k + 6, 3); WAITB(8); COMPUTE(0, X);
    }
    // after loop: computed through k=28; staged through 31; A(29) in Y.
    // ---- epilogue peels: drain 6 -> 4 -> 0 ----
    ALOAD(X, 30); AFENCE(); WAITB(6); COMPUTE(1, Y);   // k=29
    ALOAD(Y, 31); AFENCE(); WAITB(4); COMPUTE(2, X);   // k=30
    WAITB(0);                COMPUTE(3, Y);            // k=31

#undef ALOAD
#undef AFENCE
#undef STAGE
#undef WAITB
#undef COMPUTE

    // Epilogue: C/D layout col=lane&15, row=(lane>>4)*4+reg
    const int cl = lane & 15;
    const int qd = lane >> 4;
    float bv[4];
#pragma unroll
    for (int nj = 0; nj < 4; ++nj)
        bv[nj] = bias[e * D_OUT + n0 + wn + nj * 16 + cl];
#pragma unroll
    for (int mi = 0; mi < 2; ++mi) {
#pragma unroll
        for (int reg = 0; reg < 4; ++reg) {
            const int mloc = wm + mi * 16 + qd * 4 + reg;
            const int r = rows_s[mloc];
            if (r >= 0) {
                float* orow = out + (size_t)r * D_OUT + n0 + wn + cl;
#pragma unroll
                for (int nj = 0; nj < 4; ++nj)
                    orow[nj * 16] = acc[mi][nj][reg] + bv[nj];
            }
        }
    }
}

// ---------------------------------------------------------------------------
// Fallback GEMM (R2, validated; TM=64 tile list): used if ws too small.
// ---------------------------------------------------------------------------
#define TMF 64
#define TNF 128

__global__ __launch_bounds__(256) void moe_gemm_fb(
    const float* __restrict__ xs, const float* __restrict__ W,
    const float* __restrict__ bias, const int* __restrict__ ws,
    float* __restrict__ out)
{
    const int tix = blockIdx.y;
    if (tix >= ws[WS_NTILES]) return;
    const int e   = ws[WS_TILE_E + tix];
    const int m0  = ws[WS_TILE_M + tix];
    const int s0  = ws[WS_STARTS + e];
    const int cnt = ws[WS_STARTS + e + 1] - s0;
    const int n0  = blockIdx.x * TNF;

    __shared__ short Ahi[2][TMF * TK];
    __shared__ short Alo[2][TMF * TK];
    __shared__ short Bhi[2][TNF * TK];
    __shared__ short Blo[2][TNF * TK];
    __shared__ int   rows_s[TMF];

    const int t = threadIdx.x;
    if (t < TMF) {
        const int r = m0 + t;
        rows_s[t] = (r < cnt) ? ws[WS_PERM + s0 + r] : -1;
    }
    __syncthreads();

    const int lane = t & 63;
    const int wave = t >> 6;
    const int wm = (wave & 1) * 32;
    const int wn = (wave >> 1) * 64;

    const float zf = 0.f;
    f32x4 acc[2][4];
#pragma unroll
    for (int mi = 0; mi < 2; ++mi)
#pragma unroll
        for (int nj = 0; nj < 4; ++nj)
            acc[mi][nj] = (f32x4){zf, zf, zf, zf};

    const float* Wb = W + (size_t)e * (D_OUT * (size_t)D_IN) + (size_t)n0 * D_IN;

    const int j  = t & 3;
    const int rr = t >> 2;

    const int arow = rows_s[rr];
    const float* aptr = (arow >= 0) ? (xs + (size_t)arow * D_IN + j * 8) : nullptr;

    const int slotA   = (j * 16 + (rr & 15)) ^ (j << 1);
    const int aoff_st = (rr >> 4) * 512 + slotA * 8;
    const int boff0   = aoff_st;
    const int boff1   = aoff_st + 4 * 512;

    const float* qb0 = Wb + (size_t)rr * D_IN + j * 8;
    const float* qb1 = Wb + (size_t)(64 + rr) * D_IN + j * 8;

    const int rds = (lane ^ ((lane >> 4) << 1)) * 8;

#define LOAD_SET(A0, A1, B0, B1, B2, B3, KOFF) do {                          \
        const int _k = (KOFF);                                               \
        if (aptr) {                                                          \
            A0 = *(const float4*)(aptr + _k);                                \
            A1 = *(const float4*)(aptr + _k + 4);                            \
        }                                                                    \
        B0 = *(const float4*)(qb0 + _k); B1 = *(const float4*)(qb0 + _k + 4);\
        B2 = *(const float4*)(qb1 + _k); B3 = *(const float4*)(qb1 + _k + 4);\
    } while (0)

#define CVT_STORE_SET(A0, A1, B0, B1, B2, B3, BUF) do {                      \
        short8 _h, _l;                                                       \
        cvt8(A0, A1, _h, _l);                                                \
        *(short8*)&Ahi[BUF][aoff_st] = _h; *(short8*)&Alo[BUF][aoff_st] = _l;\
        cvt8(B0, B1, _h, _l);                                                \
        *(short8*)&Bhi[BUF][boff0] = _h;   *(short8*)&Blo[BUF][boff0] = _l;  \
        cvt8(B2, B3, _h, _l);                                                \
        *(short8*)&Bhi[BUF][boff1] = _h;   *(short8*)&Blo[BUF][boff1] = _l;  \
    } while (0)

#define FRAG_MFMA(BUF) do {                                                  \
        short8 ah[2], al[2], bh[4], bl[4];                                   \
        _Pragma("unroll")                                                    \
        for (int i2 = 0; i2 < 2; ++i2) {                                     \
            const int aoff = ((wm >> 4) + i2) * 512 + rds;                   \
            ah[i2] = *(const short8*)&Ahi[BUF][aoff];                        \
            al[i2] = *(const short8*)&Alo[BUF][aoff];                        \
        }                                                                    \
        _Pragma("unroll")                                                    \
        for (int i2 = 0; i2 < 4; ++i2) {                                     \
            const int boff = ((wn >> 4) + i2) * 512 + rds;                   \
            bh[i2] = *(const short8*)&Bhi[BUF][boff];                        \
            bl[i2] = *(const short8*)&Blo[BUF][boff];                        \
        }                                                                    \
        _Pragma("unroll")                                                    \
        for (int mi = 0; mi < 2; ++mi)                                       \
            _Pragma("unroll")                                                \
            for (int nj = 0; nj < 4; ++nj) {                                 \
                acc[mi][nj] = __builtin_amdgcn_mfma_f32_16x16x32_bf16(ah[mi], bh[nj], acc[mi][nj], 0, 0, 0); \
                acc[mi][nj] = __builtin_amdgcn_mfma_f32_16x16x32_bf16(ah[mi], bl[nj], acc[mi][nj], 0, 0, 0); \
                acc[mi][nj] = __builtin_amdgcn_mfma_f32_16x16x32_bf16(al[mi], bh[nj], acc[mi][nj], 0, 0, 0); \
            }                                                                \
    } while (0)

#define PIPE_BARRIER() asm volatile("s_waitcnt lgkmcnt(0)\n\ts_barrier" ::: "memory")

    float4 ax0 = make_float4(0.f, 0.f, 0.f, 0.f), ax1 = ax0;
    float4 bx0, bx1, bx2, bx3;
    float4 ay0 = make_float4(0.f, 0.f, 0.f, 0.f), ay1 = ay0;
    float4 by0, by1, by2, by3;

    LOAD_SET(ax0, ax1, bx0, bx1, bx2, bx3, 0);
    CVT_STORE_SET(ax0, ax1, bx0, bx1, bx2, bx3, 0);
    LOAD_SET(ax0, ax1, bx0, bx1, bx2, bx3, TK);
    PIPE_BARRIER();

    int ke = 2 * TK;
#pragma unroll 1
    for (int i = 0; i < 15; ++i) {
        {
            LOAD_SET(ay0, ay1, by0, by1, by2, by3, ke);
            FRAG_MFMA(0);
            CVT_STORE_SET(ax0, ax1, bx0, bx1, bx2, bx3, 1);
            PIPE_BARRIER();
        }
        {
            LOAD_SET(ax0, ax1, bx0, bx1, bx2, bx3, ke + TK);
            FRAG_MFMA(1);
            CVT_STORE_SET(ay0, ay1, by0, by1, by2, by3, 0);
            PIPE_BARRIER();
        }
        ke += 2 * TK;
    }
    {
        FRAG_MFMA(0);
        CVT_STORE_SET(ax0, ax1, bx0, bx1, bx2, bx3, 1);
        PIPE_BARRIER();
    }
    {
        FRAG_MFMA(1);
    }

#undef LOAD_SET
#undef CVT_STORE_SET
#undef FRAG_MFMA
#undef PIPE_BARRIER

    const int cl = lane & 15;
    const int qd = lane >> 4;
    float bv[4];
#pragma unroll
    for (int nj = 0; nj < 4; ++nj)
        bv[nj] = bias[e * D_OUT + n0 + wn + nj * 16 + cl];
#pragma unroll
    for (int mi = 0; mi < 2; ++mi) {
#pragma unroll
        for (int reg = 0; reg < 4; ++reg) {
            const int mloc = wm + mi * 16 + qd * 4 + reg;
            const int r = rows_s[mloc];
            if (r >= 0) {
                float* orow = out + (size_t)r * D_OUT + n0 + wn + cl;
#pragma unroll
                for (int nj = 0; nj < 4; ++nj)
                    orow[nj * 16] = acc[mi][nj][reg] + bv[nj];
            }
        }
    }
}

extern "C" void kernel_launch(void* const* d_in, const int* in_sizes, int n_in,
                              void* d_out, int out_size, void* d_ws, size_t ws_size,
                              hipStream_t stream) {
    const float* xs      = (const float*)d_in[0];
    const int*   mxs     = (const int*)d_in[1];
    const int*   actions = (const int*)d_in[2];
    const float* W       = (const float*)d_in[3];
    const float* bias    = (const float*)d_in[4];
    float* out = (float*)d_out;
    int*   ws  = (int*)d_ws;
    char*  wsb = (char*)d_ws;

    short* XhiP = (short*)(wsb + WS_XHI_OFF);
    short* XloP = (short*)(wsb + WS_XLO_OFF);
    short* WhiP = (short*)(wsb + WS_WHI_OFF);
    short* WloP = (short*)(wsb + WS_WLO_OFF);

    const int metaOff = BATCH * D_OUT;
    const int meta_mode = (out_size >= metaOff + 3 * BATCH) ? 2
                        : (out_size >= metaOff + 2 * BATCH) ? 1 : 0;

    const bool big = ws_size >= (size_t)WS_NEEDED;
    const int prep_blocks = big ? (17 + 6144) : 17;
    const int tm_tile = big ? TM5 : TMF;

    prep_kernel<<<prep_blocks, 256, 0, stream>>>(
        actions, mxs, xs, W, ws, XhiP, XloP, WhiP, WloP, out, meta_mode, tm_tile);

    if (big) {
        // grid 8*(MAX_TILES_128+1) = 320: j5 in [0,40) covers tix <= 39
        moe_gemm_pc<<<8 * (MAX_TILES_128 + 1), 512, 0, stream>>>(
            XhiP, XloP, WhiP, WloP, bias, ws, out);
    } else {
        dim3 grid(D_OUT / TNF, MAX_TILES, 1);
        moe_gemm_fb<<<grid, 256, 0, stream>>>(xs, W, bias, ws, out);
    }
}

// Round 9
// 169.890 us; speedup vs baseline: 1.0597x; 1.0597x over previous
//
#include <hip/hip_runtime.h>

#define BATCH 4096
#define D_IN 1024
#define D_OUT 1024
#define N_EXPERTS 8

#define TK 32
#define MAX_TILES 71        // TM=64 tile list bound

// ws int32 region (slots)
#define WS_PERM    0       // [4096]
#define WS_STARTS  4096    // [9]
#define WS_TILE_E  4112    // [160]
#define WS_TILE_M  4280    // [160]
#define WS_NTILES  4448    // [1]

// staged bf16 regions (byte offsets into ws)
#define WS_XHI_OFF   32768
#define WS_XLO_OFF   (32768 + 8388608)
#define WS_WHI_OFF   (32768 + 2*8388608)
#define WS_WLO_OFF   (32768 + 2*8388608 + 16777216)
#define WS_NEEDED    (32768 + 2*8388608 + 2*16777216)   // 50,364,416 B

typedef __attribute__((ext_vector_type(8))) short short8;   // 8 x bf16
typedef __attribute__((ext_vector_type(4))) float f32x4;

// fp32 -> bf16 hi/lo split (truncation; lo = next 8 mantissa bits). Unchanged.
__device__ __forceinline__ void cvt8(const float4 a, const float4 b,
                                     short8& h, short8& l) {
    float f[8] = {a.x, a.y, a.z, a.w, b.x, b.y, b.z, b.w};
#pragma unroll
    for (int i = 0; i < 8; ++i) {
        const unsigned u = __float_as_uint(f[i]);
        h[i] = (short)(u >> 16);
        const float r = f[i] - __uint_as_float(u & 0xffff0000u);
        l[i] = (short)(__float_as_uint(r) >> 16);
    }
}

// ---------------------------------------------------------------------------
// Fused prep kernel (validated R3-R8). tm_tile = 64 here (both paths).
// ---------------------------------------------------------------------------
__global__ __launch_bounds__(256) void prep_kernel(
    const int* __restrict__ actions, const int* __restrict__ mxs,
    const float* __restrict__ xs, const float* __restrict__ W,
    int* __restrict__ ws,
    short* __restrict__ XhiP, short* __restrict__ XloP,
    short* __restrict__ WhiP, short* __restrict__ WloP,
    float* __restrict__ out, int meta_mode, int tm_tile)
{
    const int bid = blockIdx.x;
    const int t = threadIdx.x;

    if (bid == 0) {
        __shared__ int chunkoff[64][N_EXPERTS];
        const int lane = t & 63;
        const int wave = t >> 6;

        for (int it = 0; it < 16; ++it) {
            const int c = wave * 16 + it;
            const int a = actions[c * 64 + lane];
            int myc = 0;
#pragma unroll
            for (int e = 0; e < N_EXPERTS; ++e) {
                const unsigned long long me = __ballot(a == e);
                if (lane == e) myc = (int)__popcll(me);
            }
            if (lane < N_EXPERTS) chunkoff[c][lane] = myc;
        }
        __syncthreads();

        if (wave == 0) {
            int cc0 = chunkoff[lane][0], cc1 = chunkoff[lane][1];
            int cc2 = chunkoff[lane][2], cc3 = chunkoff[lane][3];
            int cc4 = chunkoff[lane][4], cc5 = chunkoff[lane][5];
            int cc6 = chunkoff[lane][6], cc7 = chunkoff[lane][7];
            int tot0, tot1, tot2, tot3, tot4, tot5, tot6, tot7;
            int ex0, ex1, ex2, ex3, ex4, ex5, ex6, ex7;
#define SCAN1(CC, TOT, EX) do {                                   \
            int v = CC;                                           \
            _Pragma("unroll")                                     \
            for (int d = 1; d < 64; d <<= 1) {                    \
                const int u = __shfl_up(v, d, 64);                \
                if (lane >= d) v += u;                            \
            }                                                     \
            TOT = __shfl(v, 63, 64);                              \
            EX = v - CC;                                          \
        } while (0)
            SCAN1(cc0, tot0, ex0); SCAN1(cc1, tot1, ex1);
            SCAN1(cc2, tot2, ex2); SCAN1(cc3, tot3, ex3);
            SCAN1(cc4, tot4, ex4); SCAN1(cc5, tot5, ex5);
            SCAN1(cc6, tot6, ex6); SCAN1(cc7, tot7, ex7);
#undef SCAN1
            const int b0 = 0;
            const int b1 = b0 + tot0, b2 = b1 + tot1, b3 = b2 + tot2;
            const int b4 = b3 + tot3, b5 = b4 + tot4, b6 = b5 + tot5;
            const int b7 = b6 + tot6;
            chunkoff[lane][0] = b0 + ex0; chunkoff[lane][1] = b1 + ex1;
            chunkoff[lane][2] = b2 + ex2; chunkoff[lane][3] = b3 + ex3;
            chunkoff[lane][4] = b4 + ex4; chunkoff[lane][5] = b5 + ex5;
            chunkoff[lane][6] = b6 + ex6; chunkoff[lane][7] = b7 + ex7;
            if (lane == 0) {
                ws[WS_STARTS + 0] = b0; ws[WS_STARTS + 1] = b1;
                ws[WS_STARTS + 2] = b2; ws[WS_STARTS + 3] = b3;
                ws[WS_STARTS + 4] = b4; ws[WS_STARTS + 5] = b5;
                ws[WS_STARTS + 6] = b6; ws[WS_STARTS + 7] = b7;
                ws[WS_STARTS + 8] = BATCH;
                int nt = 0;
                int tots[8] = {tot0, tot1, tot2, tot3, tot4, tot5, tot6, tot7};
#pragma unroll
                for (int e = 0; e < N_EXPERTS; ++e)
                    for (int m0 = 0; m0 < tots[e]; m0 += tm_tile) {
                        ws[WS_TILE_E + nt] = e;
                        ws[WS_TILE_M + nt] = m0;
                        ++nt;
                    }
                ws[WS_NTILES] = nt;
            }
        }
        __syncthreads();

        for (int it = 0; it < 16; ++it) {
            const int c = wave * 16 + it;
            const int i = c * 64 + lane;
            const int a = actions[i];
            unsigned long long msel = 0;
#pragma unroll
            for (int e = 0; e < N_EXPERTS; ++e) {
                const unsigned long long me = __ballot(a == e);
                if (a == e) msel = me;
            }
            const int rank = (int)__popcll(msel & ((1ull << lane) - 1ull));
            const int pos = chunkoff[c][a] + rank;
            ws[WS_PERM + pos] = i;
        }
        return;
    }

    if (bid <= 16) {
        const int i = (bid - 1) * 256 + t;
        if (meta_mode == 2) {
            out[BATCH * D_OUT + i] = (float)mxs[i];
            long long* a64 = (long long*)(out + BATCH * D_OUT + BATCH);
            a64[i] = (long long)actions[i];
        } else if (meta_mode == 1) {
            out[BATCH * D_OUT + i] = (float)mxs[i];
            out[BATCH * D_OUT + BATCH + i] = (float)actions[i];
        }
        return;
    }

    const int g = (bid - 17) * 256 + t;
    if (g < 1048576) {
        // g = (((e*32+kt)*8+nt)*8 + i2)*64 + slot ; slot = j*16 + c
        const int slot = g & 63;
        const int i2   = (g >> 6) & 7;
        const int blk  = g >> 9;
        const int nt   = blk & 7;
        const int kt   = (blk >> 3) & 31;
        const int e    = blk >> 8;
        const int c    = slot & 15;
        const int j    = slot >> 4;
        const int n    = nt * 128 + i2 * 16 + c;
        const float* p = W + ((size_t)(e << 10) + n) * D_IN + kt * 32 + j * 8;
        const float4 f0 = *(const float4*)p;
        const float4 f1 = *(const float4*)(p + 4);
        short8 h, l;
        cvt8(f0, f1, h, l);
        *(short8*)(WhiP + (size_t)g * 8) = h;
        *(short8*)(WloP + (size_t)g * 8) = l;
    } else {
        const int g2 = g - 1048576;   // < 524288
        const float* p = xs + (size_t)g2 * 8;
        const float4 f0 = *(const float4*)p;
        const float4 f1 = *(const float4*)(p + 4);
        short8 h, l;
        cvt8(f0, f1, h, l);
        *(short8*)(XhiP + (size_t)g2 * 8) = h;
        *(short8*)(XloP + (size_t)g2 * 8) = l;
    }
}

// ---------------------------------------------------------------------------
// R9 GEMM: the untested cell of the matrix — DEEP PIPELINE *AND* 2 blocks/CU
// *AND* ~one scheduling round.
//   R6: depth-3, 128x128, 129KB LDS -> 1 blk/CU, 312 blks = 2 rounds = 61us
//       (per-round ~30us: pipeline works).
//   R5: depth-1 window, 128x128, 66KB -> 2 blk/CU, 1 round = 49us (stalls).
// Here: 64x128 tile (validated R4), THREE buffers (24KB each = 72KB ->
// 2 blk/CU), R6's exact single-barrier schedule:
//   phase t: [vmcnt(6) lgkmcnt(0); s_barrier] -> STAGE(t+2) -> FRAG(t%3)
// vmcnt(6): steady 12 outstanding (2 stages x 6 uniform loads); oldest 6 =
// this phase's buffer. lgkmcnt(0) before barrier: this wave's ds_reads of
// buf[(t-1)%3] drained, so STAGE(t+2) into that same buffer after the
// barrier cannot race (R6-proven argument). Stage->wait window = 2 phases
// >> DMA latency. No register pipelines for the compiler to defeat —
// everything is global_load_lds + asm barriers (R4/R6 refcheck-clean).
// Grid 568 @ 2/CU = 1.11 rounds.
// ---------------------------------------------------------------------------
#define TM9 64
#define TN9 128

__global__ __launch_bounds__(256) void moe_gemm_pc(
    const short* __restrict__ Xhi, const short* __restrict__ Xlo,
    const short* __restrict__ Whi, const short* __restrict__ Wlo,
    const float* __restrict__ bias, const int* __restrict__ ws,
    float* __restrict__ out)
{
    const int wid = blockIdx.x;
    const int nsl = wid & 7;         // n-slice 0..7 (one per XCD round-robin)
    const int tix = wid >> 3;        // tile 0..70
    if (tix >= ws[WS_NTILES]) return;
    const int e   = ws[WS_TILE_E + tix];
    const int m0  = ws[WS_TILE_M + tix];
    const int s0  = ws[WS_STARTS + e];
    const int cnt = ws[WS_STARTS + e + 1] - s0;
    const int n0  = nsl * TN9;

    __shared__ short Ahi[3][4 * 512];   // [buf][frag-tile(4)][slot(64)][8]
    __shared__ short Alo[3][4 * 512];
    __shared__ short Bhi[3][8 * 512];   // [buf][frag-tile(8)][slot(64)][8]
    __shared__ short Blo[3][8 * 512];
    __shared__ int   rows_s[TM9];

    const int t = threadIdx.x;
    if (t < TM9) {
        const int r = m0 + t;
        rows_s[t] = (r < cnt) ? ws[WS_PERM + s0 + r] : -1;
    }
    __syncthreads();

    const int lane = t & 63;
    const int wave = t >> 6;          // 0..3
    const int wm = (wave & 1) * 32;   // quadrant m base (0,32)
    const int wn = (wave >> 1) * 64;  // quadrant n base (0,64)

    const float zf = 0.f;
    f32x4 acc[2][4];
#pragma unroll
    for (int mi = 0; mi < 2; ++mi)
#pragma unroll
        for (int nj = 0; nj < 4; ++nj)
            acc[mi][nj] = (f32x4){zf, zf, zf, zf};

    // A staging: wave w stages frag tile w; lane l -> row w*16+(l&15),
    // k-octet l>>4. Clamped row for pads (uniform 6 loads/STAGE/wave keeps
    // the vmcnt arithmetic exact); pad-row acc garbage, never stored.
    const int arow0 = rows_s[wave * 16 + (lane & 15)];
    const int arow  = arow0 < 0 ? 0 : arow0;
    const short* aSrcHi = Xhi + (size_t)arow * D_IN + (lane >> 4) * 8;
    const short* aSrcLo = Xlo + (size_t)arow * D_IN + (lane >> 4) * 8;

    // B staging: staged block ((e*32+kt)*8+nsl)*4096 shorts; wave w stages
    // frag tiles w and w+4 (contiguous 1KB each).
    const size_t wBase = ((size_t)e * 256 + (size_t)nsl) * 4096;
    const size_t bo0 = (size_t)wave * 512 + lane * 8;
    const size_t bo1 = (size_t)(wave + 4) * 512 + lane * 8;

#define STAGE(KT, BUF) do {                                                    \
        const int _kt = (KT);                                                  \
        __builtin_amdgcn_global_load_lds(                                      \
            (const __attribute__((address_space(1))) void*)(aSrcHi + _kt * 32),\
            (__attribute__((address_space(3))) void*)&Ahi[BUF][wave * 512],    \
            16, 0, 0);                                                         \
        __builtin_amdgcn_global_load_lds(                                      \
            (const __attribute__((address_space(1))) void*)(aSrcLo + _kt * 32),\
            (__attribute__((address_space(3))) void*)&Alo[BUF][wave * 512],    \
            16, 0, 0);                                                         \
        {                                                                      \
            const size_t _wo = wBase + (size_t)_kt * 32768;                    \
            __builtin_amdgcn_global_load_lds(                                  \
                (const __attribute__((address_space(1))) void*)(Whi + _wo + bo0), \
                (__attribute__((address_space(3))) void*)&Bhi[BUF][wave * 512],\
                16, 0, 0);                                                     \
            __builtin_amdgcn_global_load_lds(                                  \
                (const __attribute__((address_space(1))) void*)(Wlo + _wo + bo0), \
                (__attribute__((address_space(3))) void*)&Blo[BUF][wave * 512],\
                16, 0, 0);                                                     \
            __builtin_amdgcn_global_load_lds(                                  \
                (const __attribute__((address_space(1))) void*)(Whi + _wo + bo1), \
                (__attribute__((address_space(3))) void*)&Bhi[BUF][(wave + 4) * 512], \
                16, 0, 0);                                                     \
            __builtin_amdgcn_global_load_lds(                                  \
                (const __attribute__((address_space(1))) void*)(Wlo + _wo + bo1), \
                (__attribute__((address_space(3))) void*)&Blo[BUF][(wave + 4) * 512], \
                16, 0, 0);                                                     \
        }                                                                      \
    } while (0)

    const int rds = lane * 8;   // linear fragment read, conflict-free

#define FRAG_MFMA(BUF) do {                                                  \
        short8 ah[2], al[2], bh[4], bl[4];                                   \
        _Pragma("unroll")                                                    \
        for (int i2 = 0; i2 < 2; ++i2) {                                     \
            const int aoff = ((wm >> 4) + i2) * 512 + rds;                   \
            ah[i2] = *(const short8*)&Ahi[BUF][aoff];                        \
            al[i2] = *(const short8*)&Alo[BUF][aoff];                        \
        }                                                                    \
        _Pragma("unroll")                                                    \
        for (int i2 = 0; i2 < 4; ++i2) {                                     \
            const int boff = ((wn >> 4) + i2) * 512 + rds;                   \
            bh[i2] = *(const short8*)&Bhi[BUF][boff];                        \
            bl[i2] = *(const short8*)&Blo[BUF][boff];                        \
        }                                                                    \
        _Pragma("unroll")                                                    \
        for (int mi = 0; mi < 2; ++mi)                                       \
            _Pragma("unroll")                                                \
            for (int nj = 0; nj < 4; ++nj) {                                 \
                acc[mi][nj] = __builtin_amdgcn_mfma_f32_16x16x32_bf16(ah[mi], bh[nj], acc[mi][nj], 0, 0, 0); \
                acc[mi][nj] = __builtin_amdgcn_mfma_f32_16x16x32_bf16(ah[mi], bl[nj], acc[mi][nj], 0, 0, 0); \
                acc[mi][nj] = __builtin_amdgcn_mfma_f32_16x16x32_bf16(al[mi], bh[nj], acc[mi][nj], 0, 0, 0); \
            }                                                                \
    } while (0)

    // R6's proven barrier: counted vmcnt + full lgkm drain + s_barrier.
#define WAIT6_BAR() asm volatile("s_waitcnt vmcnt(6) lgkmcnt(0)\n\ts_barrier" ::: "memory")
#define WAIT0_BAR() asm volatile("s_waitcnt vmcnt(0) lgkmcnt(0)\n\ts_barrier" ::: "memory")

    // prologue: stage tiles 0,1 -> 12 outstanding per wave
    STAGE(0, 0);
    STAGE(1, 1);

    // phases 0..29 (10 x unroll-3): phase t waits buf t%3, stages t+2
    int kt = 2;
#pragma unroll 1
    for (int i = 0; i < 10; ++i) {
        WAIT6_BAR(); STAGE(kt,     2); FRAG_MFMA(0);
        WAIT6_BAR(); STAGE(kt + 1, 0); FRAG_MFMA(1);
        WAIT6_BAR(); STAGE(kt + 2, 1); FRAG_MFMA(2);
        kt += 3;
    }
    // drain: tiles 30 (buf0), 31 (buf1)
    WAIT6_BAR(); FRAG_MFMA(0);
    WAIT0_BAR(); FRAG_MFMA(1);

#undef STAGE
#undef FRAG_MFMA
#undef WAIT6_BAR
#undef WAIT0_BAR

    // Epilogue: C/D layout col=lane&15, row=(lane>>4)*4+reg
    const int cl = lane & 15;
    const int qd = lane >> 4;
    float bv[4];
#pragma unroll
    for (int nj = 0; nj < 4; ++nj)
        bv[nj] = bias[e * D_OUT + n0 + wn + nj * 16 + cl];
#pragma unroll
    for (int mi = 0; mi < 2; ++mi) {
#pragma unroll
        for (int reg = 0; reg < 4; ++reg) {
            const int mloc = wm + mi * 16 + qd * 4 + reg;
            const int r = rows_s[mloc];
            if (r >= 0) {
                float* orow = out + (size_t)r * D_OUT + n0 + wn + cl;
#pragma unroll
                for (int nj = 0; nj < 4; ++nj)
                    orow[nj * 16] = acc[mi][nj][reg] + bv[nj];
            }
        }
    }
}

// ---------------------------------------------------------------------------
// Fallback GEMM (R2, validated; TM=64 tile list): used if ws too small.
// ---------------------------------------------------------------------------
#define TMF 64
#define TNF 128

__global__ __launch_bounds__(256) void moe_gemm_fb(
    const float* __restrict__ xs, const float* __restrict__ W,
    const float* __restrict__ bias, const int* __restrict__ ws,
    float* __restrict__ out)
{
    const int tix = blockIdx.y;
    if (tix >= ws[WS_NTILES]) return;
    const int e   = ws[WS_TILE_E + tix];
    const int m0  = ws[WS_TILE_M + tix];
    const int s0  = ws[WS_STARTS + e];
    const int cnt = ws[WS_STARTS + e + 1] - s0;
    const int n0  = blockIdx.x * TNF;

    __shared__ short Ahi[2][TMF * TK];
    __shared__ short Alo[2][TMF * TK];
    __shared__ short Bhi[2][TNF * TK];
    __shared__ short Blo[2][TNF * TK];
    __shared__ int   rows_s[TMF];

    const int t = threadIdx.x;
    if (t < TMF) {
        const int r = m0 + t;
        rows_s[t] = (r < cnt) ? ws[WS_PERM + s0 + r] : -1;
    }
    __syncthreads();

    const int lane = t & 63;
    const int wave = t >> 6;
    const int wm = (wave & 1) * 32;
    const int wn = (wave >> 1) * 64;

    const float zf = 0.f;
    f32x4 acc[2][4];
#pragma unroll
    for (int mi = 0; mi < 2; ++mi)
#pragma unroll
        for (int nj = 0; nj < 4; ++nj)
            acc[mi][nj] = (f32x4){zf, zf, zf, zf};

    const float* Wb = W + (size_t)e * (D_OUT * (size_t)D_IN) + (size_t)n0 * D_IN;

    const int j  = t & 3;
    const int rr = t >> 2;

    const int arow = rows_s[rr];
    const float* aptr = (arow >= 0) ? (xs + (size_t)arow * D_IN + j * 8) : nullptr;

    const int slotA   = (j * 16 + (rr & 15)) ^ (j << 1);
    const int aoff_st = (rr >> 4) * 512 + slotA * 8;
    const int boff0   = aoff_st;
    const int boff1   = aoff_st + 4 * 512;

    const float* qb0 = Wb + (size_t)rr * D_IN + j * 8;
    const float* qb1 = Wb + (size_t)(64 + rr) * D_IN + j * 8;

    const int rds = (lane ^ ((lane >> 4) << 1)) * 8;

#define LOAD_SET(A0, A1, B0, B1, B2, B3, KOFF) do {                          \
        const int _k = (KOFF);                                               \
        if (aptr) {                                                          \
            A0 = *(const float4*)(aptr + _k);                                \
            A1 = *(const float4*)(aptr + _k + 4);                            \
        }                                                                    \
        B0 = *(const float4*)(qb0 + _k); B1 = *(const float4*)(qb0 + _k + 4);\
        B2 = *(const float4*)(qb1 + _k); B3 = *(const float4*)(qb1 + _k + 4);\
    } while (0)

#define CVT_STORE_SET(A0, A1, B0, B1, B2, B3, BUF) do {                      \
        short8 _h, _l;                                                       \
        cvt8(A0, A1, _h, _l);                                                \
        *(short8*)&Ahi[BUF][aoff_st] = _h; *(short8*)&Alo[BUF][aoff_st] = _l;\
        cvt8(B0, B1, _h, _l);                                                \
        *(short8*)&Bhi[BUF][boff0] = _h;   *(short8*)&Blo[BUF][boff0] = _l;  \
        cvt8(B2, B3, _h, _l);                                                \
        *(short8*)&Bhi[BUF][boff1] = _h;   *(short8*)&Blo[BUF][boff1] = _l;  \
    } while (0)

#define FRAG_MFMA(BUF) do {                                                  \
        short8 ah[2], al[2], bh[4], bl[4];                                   \
        _Pragma("unroll")                                                    \
        for (int i2 = 0; i2 < 2; ++i2) {                                     \
            const int aoff = ((wm >> 4) + i2) * 512 + rds;                   \
            ah[i2] = *(const short8*)&Ahi[BUF][aoff];                        \
            al[i2] = *(const short8*)&Alo[BUF][aoff];                        \
        }                                                                    \
        _Pragma("unroll")                                                    \
        for (int i2 = 0; i2 < 4; ++i2) {                                     \
            const int boff = ((wn >> 4) + i2) * 512 + rds;                   \
            bh[i2] = *(const short8*)&Bhi[BUF][boff];                        \
            bl[i2] = *(const short8*)&Blo[BUF][boff];                        \
        }                                                                    \
        _Pragma("unroll")                                                    \
        for (int mi = 0; mi < 2; ++mi)                                       \
            _Pragma("unroll")                                                \
            for (int nj = 0; nj < 4; ++nj) {                                 \
                acc[mi][nj] = __builtin_amdgcn_mfma_f32_16x16x32_bf16(ah[mi], bh[nj], acc[mi][nj], 0, 0, 0); \
                acc[mi][nj] = __builtin_amdgcn_mfma_f32_16x16x32_bf16(ah[mi], bl[nj], acc[mi][nj], 0, 0, 0); \
                acc[mi][nj] = __builtin_amdgcn_mfma_f32_16x16x32_bf16(al[mi], bh[nj], acc[mi][nj], 0, 0, 0); \
            }                                                                \
    } while (0)

#define PIPE_BARRIER() asm volatile("s_waitcnt lgkmcnt(0)\n\ts_barrier" ::: "memory")

    float4 ax0 = make_float4(0.f, 0.f, 0.f, 0.f), ax1 = ax0;
    float4 bx0, bx1, bx2, bx3;
    float4 ay0 = make_float4(0.f, 0.f, 0.f, 0.f), ay1 = ay0;
    float4 by0, by1, by2, by3;

    LOAD_SET(ax0, ax1, bx0, bx1, bx2, bx3, 0);
    CVT_STORE_SET(ax0, ax1, bx0, bx1, bx2, bx3, 0);
    LOAD_SET(ax0, ax1, bx0, bx1, bx2, bx3, TK);
    PIPE_BARRIER();

    int ke = 2 * TK;
#pragma unroll 1
    for (int i = 0; i < 15; ++i) {
        {
            LOAD_SET(ay0, ay1, by0, by1, by2, by3, ke);
            FRAG_MFMA(0);
            CVT_STORE_SET(ax0, ax1, bx0, bx1, bx2, bx3, 1);
            PIPE_BARRIER();
        }
        {
            LOAD_SET(ax0, ax1, bx0, bx1, bx2, bx3, ke + TK);
            FRAG_MFMA(1);
            CVT_STORE_SET(ay0, ay1, by0, by1, by2, by3, 0);
            PIPE_BARRIER();
        }
        ke += 2 * TK;
    }
    {
        FRAG_MFMA(0);
        CVT_STORE_SET(ax0, ax1, bx0, bx1, bx2, bx3, 1);
        PIPE_BARRIER();
    }
    {
        FRAG_MFMA(1);
    }

#undef LOAD_SET
#undef CVT_STORE_SET
#undef FRAG_MFMA
#undef PIPE_BARRIER

    const int cl = lane & 15;
    const int qd = lane >> 4;
    float bv[4];
#pragma unroll
    for (int nj = 0; nj < 4; ++nj)
        bv[nj] = bias[e * D_OUT + n0 + wn + nj * 16 + cl];
#pragma unroll
    for (int mi = 0; mi < 2; ++mi) {
#pragma unroll
        for (int reg = 0; reg < 4; ++reg) {
            const int mloc = wm + mi * 16 + qd * 4 + reg;
            const int r = rows_s[mloc];
            if (r >= 0) {
                float* orow = out + (size_t)r * D_OUT + n0 + wn + cl;
#pragma unroll
                for (int nj = 0; nj < 4; ++nj)
                    orow[nj * 16] = acc[mi][nj][reg] + bv[nj];
            }
        }
    }
}

extern "C" void kernel_launch(void* const* d_in, const int* in_sizes, int n_in,
                              void* d_out, int out_size, void* d_ws, size_t ws_size,
                              hipStream_t stream) {
    const float* xs      = (const float*)d_in[0];
    const int*   mxs     = (const int*)d_in[1];
    const int*   actions = (const int*)d_in[2];
    const float* W       = (const float*)d_in[3];
    const float* bias    = (const float*)d_in[4];
    float* out = (float*)d_out;
    int*   ws  = (int*)d_ws;
    char*  wsb = (char*)d_ws;

    short* XhiP = (short*)(wsb + WS_XHI_OFF);
    short* XloP = (short*)(wsb + WS_XLO_OFF);
    short* WhiP = (short*)(wsb + WS_WHI_OFF);
    short* WloP = (short*)(wsb + WS_WLO_OFF);

    const int metaOff = BATCH * D_OUT;
    const int meta_mode = (out_size >= metaOff + 3 * BATCH) ? 2
                        : (out_size >= metaOff + 2 * BATCH) ? 1 : 0;

    const bool big = ws_size >= (size_t)WS_NEEDED;
    const int prep_blocks = big ? (17 + 6144) : 17;

    prep_kernel<<<prep_blocks, 256, 0, stream>>>(
        actions, mxs, xs, W, ws, XhiP, XloP, WhiP, WloP, out, meta_mode, TM9);

    if (big) {
        moe_gemm_pc<<<8 * MAX_TILES, 256, 0, stream>>>(
            XhiP, XloP, WhiP, WloP, bias, ws, out);
    } else {
        dim3 grid(D_OUT / TNF, MAX_TILES, 1);
        moe_gemm_fb<<<grid, 256, 0, stream>>>(xs, W, bias, ws, out);
    }
}

// Round 10
// 141.213 us; speedup vs baseline: 1.2750x; 1.2031x over previous
//
#include <hip/hip_runtime.h>

#define BATCH 4096
#define D_IN 1024
#define D_OUT 1024
#define N_EXPERTS 8

#define TK 32
#define TMX 128
#define TNX 128
#define MAX_TILES_128 39    // sum ceil(c_e/128) <= 32 + 7

// ws int32 region (slots) — only region used; no staging workspace.
#define WS_PERM    0       // [4096]
#define WS_STARTS  4096    // [9]
#define WS_TILE_E  4112    // [40]
#define WS_TILE_M  4160    // [40]
#define WS_NTILES  4208    // [1]

typedef __attribute__((ext_vector_type(8))) short short8;   // 8 x bf16
typedef __attribute__((ext_vector_type(4))) float f32x4;

// fp32 -> bf16 hi/lo split (truncation; lo = next 8 mantissa bits). Unchanged
// from R0-R9 (absmax 0.03125 across all rounds).
__device__ __forceinline__ void cvt8(const float4 a, const float4 b,
                                     short8& h, short8& l) {
    float f[8] = {a.x, a.y, a.z, a.w, b.x, b.y, b.z, b.w};
#pragma unroll
    for (int i = 0; i < 8; ++i) {
        const unsigned u = __float_as_uint(f[i]);
        h[i] = (short)(u >> 16);
        const float r = f[i] - __uint_as_float(u & 0xffff0000u);
        l[i] = (short)(__float_as_uint(r) >> 16);
    }
}

// ---------------------------------------------------------------------------
// R10: fused ballot-group (block 0, validated R3-R9) + meta tail (blocks
// 1..16). No W/X pre-staging: bookkeeping across rounds showed prep (~17us)
// only pays if gemm < ~36us, which 7 schedule variants refuted.
// ---------------------------------------------------------------------------
__global__ __launch_bounds__(256) void group_meta_kernel(
    const int* __restrict__ actions, const int* __restrict__ mxs,
    int* __restrict__ ws, float* __restrict__ out, int meta_mode)
{
    const int bid = blockIdx.x;
    const int t = threadIdx.x;

    if (bid == 0) {
        __shared__ int chunkoff[64][N_EXPERTS];
        const int lane = t & 63;
        const int wave = t >> 6;

        for (int it = 0; it < 16; ++it) {
            const int c = wave * 16 + it;
            const int a = actions[c * 64 + lane];
            int myc = 0;
#pragma unroll
            for (int e = 0; e < N_EXPERTS; ++e) {
                const unsigned long long me = __ballot(a == e);
                if (lane == e) myc = (int)__popcll(me);
            }
            if (lane < N_EXPERTS) chunkoff[c][lane] = myc;
        }
        __syncthreads();

        if (wave == 0) {
            int cc0 = chunkoff[lane][0], cc1 = chunkoff[lane][1];
            int cc2 = chunkoff[lane][2], cc3 = chunkoff[lane][3];
            int cc4 = chunkoff[lane][4], cc5 = chunkoff[lane][5];
            int cc6 = chunkoff[lane][6], cc7 = chunkoff[lane][7];
            int tot0, tot1, tot2, tot3, tot4, tot5, tot6, tot7;
            int ex0, ex1, ex2, ex3, ex4, ex5, ex6, ex7;
#define SCAN1(CC, TOT, EX) do {                                   \
            int v = CC;                                           \
            _Pragma("unroll")                                     \
            for (int d = 1; d < 64; d <<= 1) {                    \
                const int u = __shfl_up(v, d, 64);                \
                if (lane >= d) v += u;                            \
            }                                                     \
            TOT = __shfl(v, 63, 64);                              \
            EX = v - CC;                                          \
        } while (0)
            SCAN1(cc0, tot0, ex0); SCAN1(cc1, tot1, ex1);
            SCAN1(cc2, tot2, ex2); SCAN1(cc3, tot3, ex3);
            SCAN1(cc4, tot4, ex4); SCAN1(cc5, tot5, ex5);
            SCAN1(cc6, tot6, ex6); SCAN1(cc7, tot7, ex7);
#undef SCAN1
            const int b0 = 0;
            const int b1 = b0 + tot0, b2 = b1 + tot1, b3 = b2 + tot2;
            const int b4 = b3 + tot3, b5 = b4 + tot4, b6 = b5 + tot5;
            const int b7 = b6 + tot6;
            chunkoff[lane][0] = b0 + ex0; chunkoff[lane][1] = b1 + ex1;
            chunkoff[lane][2] = b2 + ex2; chunkoff[lane][3] = b3 + ex3;
            chunkoff[lane][4] = b4 + ex4; chunkoff[lane][5] = b5 + ex5;
            chunkoff[lane][6] = b6 + ex6; chunkoff[lane][7] = b7 + ex7;
            if (lane == 0) {
                ws[WS_STARTS + 0] = b0; ws[WS_STARTS + 1] = b1;
                ws[WS_STARTS + 2] = b2; ws[WS_STARTS + 3] = b3;
                ws[WS_STARTS + 4] = b4; ws[WS_STARTS + 5] = b5;
                ws[WS_STARTS + 6] = b6; ws[WS_STARTS + 7] = b7;
                ws[WS_STARTS + 8] = BATCH;
                int nt = 0;
                int tots[8] = {tot0, tot1, tot2, tot3, tot4, tot5, tot6, tot7};
#pragma unroll
                for (int e = 0; e < N_EXPERTS; ++e)
                    for (int m0 = 0; m0 < tots[e]; m0 += TMX) {
                        ws[WS_TILE_E + nt] = e;
                        ws[WS_TILE_M + nt] = m0;
                        ++nt;
                    }
                ws[WS_NTILES] = nt;
            }
        }
        __syncthreads();

        for (int it = 0; it < 16; ++it) {
            const int c = wave * 16 + it;
            const int i = c * 64 + lane;
            const int a = actions[i];
            unsigned long long msel = 0;
#pragma unroll
            for (int e = 0; e < N_EXPERTS; ++e) {
                const unsigned long long me = __ballot(a == e);
                if (a == e) msel = me;
            }
            const int rank = (int)__popcll(msel & ((1ull << lane) - 1ull));
            const int pos = chunkoff[c][a] + rank;
            ws[WS_PERM + pos] = i;
        }
        return;
    }

    // meta tail
    const int i = (bid - 1) * 256 + t;
    if (meta_mode == 2) {
        out[BATCH * D_OUT + i] = (float)mxs[i];
        long long* a64 = (long long*)(out + BATCH * D_OUT + BATCH);
        a64[i] = (long long)actions[i];
    } else if (meta_mode == 1) {
        out[BATCH * D_OUT + i] = (float)mxs[i];
        out[BATCH * D_OUT + BATCH + i] = (float)actions[i];
    }
}

// ---------------------------------------------------------------------------
// R10 GEMM: R2's VALIDATED reg-staged double-buffer loop (53us at 64x128)
// scaled to the 128x128 tile (R5-validated geometry, -33% request traffic).
// 512 threads / 8 waves in a 4x2 quadrant grid; each wave computes 32x64 as
// 2x4 16x16x32 MFMA tiles, 3 MFMA each (hi*hi + hi*lo + lo*hi).
// Per thread per K-step: 4 float4 global loads (2 A gathered-row, 2 B) ->
// 2 cvt8 -> 4 short8 LDS writes (XOR-swizzled, conflict-free since R1).
// Two named register sets X/Y (rule #20); next tile's loads issue before
// current tile's MFMAs; raw lgkm(0)+s_barrier leaves globals in flight.
// LDS 64.5KB -> 2 blocks/CU; grid 8x39 = 312 blocks = ONE round.
// No __launch_bounds__ min-waves (R8 lesson: forcing VGPR caps -> scratch
// spill); per-thread sets are SMALLER than R2's (4 vs 6 float4/set).
// ---------------------------------------------------------------------------
__global__ __launch_bounds__(512) void moe_gemm(
    const float* __restrict__ xs, const float* __restrict__ W,
    const float* __restrict__ bias, const int* __restrict__ ws,
    float* __restrict__ out)
{
    const int tix = blockIdx.y;
    if (tix >= ws[WS_NTILES]) return;
    const int e   = ws[WS_TILE_E + tix];
    const int m0  = ws[WS_TILE_M + tix];
    const int s0  = ws[WS_STARTS + e];
    const int cnt = ws[WS_STARTS + e + 1] - s0;
    const int n0  = blockIdx.x * TNX;

    // fragment-major: [tile(8)][slot(64)][8] shorts, slot XOR-swizzled
    __shared__ short Ahi[2][8 * 512];
    __shared__ short Alo[2][8 * 512];
    __shared__ short Bhi[2][8 * 512];
    __shared__ short Blo[2][8 * 512];
    __shared__ int   rows_s[TMX];

    const int t = threadIdx.x;
    if (t < TMX) {
        const int r = m0 + t;
        rows_s[t] = (r < cnt) ? ws[WS_PERM + s0 + r] : -1;
    }
    __syncthreads();

    const int lane = t & 63;
    const int wave = t >> 6;          // 0..7
    const int wm = (wave >> 1) * 32;  // quadrant m base (0,32,64,96)
    const int wn = (wave & 1) * 64;   // quadrant n base (0,64)

    const float zf = 0.f;
    f32x4 acc[2][4];
#pragma unroll
    for (int mi = 0; mi < 2; ++mi)
#pragma unroll
        for (int nj = 0; nj < 4; ++nj)
            acc[mi][nj] = (f32x4){zf, zf, zf, zf};

    const float* Wb = W + (size_t)e * (D_OUT * (size_t)D_IN) + (size_t)n0 * D_IN;

    const int j  = t & 3;    // k-octet: k = j*8 .. j*8+7
    const int rr = t >> 2;   // 0..127 (A row index AND B row index)

    const int arow = rows_s[rr];
    const float* aptr = (arow >= 0) ? (xs + (size_t)arow * D_IN + j * 8) : nullptr;

    // Swizzled store offset (loop-invariant). slot = j*16+(rr&15) ^ (j<<1);
    // tile = rr>>4 in 0..7. Same formula for A and B (both 128 rows).
    const int slotS  = (j * 16 + (rr & 15)) ^ (j << 1);
    const int off_st = (rr >> 4) * 512 + slotS * 8;   // shorts

    const float* qb = Wb + (size_t)rr * D_IN + j * 8;

    // Swizzled read offset: lane l's slot stored at l ^ ((l>>4)<<1)
    const int rds = (lane ^ ((lane >> 4) << 1)) * 8;  // shorts

#define LOAD_SET(A0, A1, B0, B1, KOFF) do {                                  \
        const int _k = (KOFF);                                               \
        if (aptr) {                                                          \
            A0 = *(const float4*)(aptr + _k);                                \
            A1 = *(const float4*)(aptr + _k + 4);                            \
        }                                                                    \
        B0 = *(const float4*)(qb + _k); B1 = *(const float4*)(qb + _k + 4);  \
    } while (0)

#define CVT_STORE_SET(A0, A1, B0, B1, BUF) do {                              \
        short8 _h, _l;                                                       \
        cvt8(A0, A1, _h, _l);                                                \
        *(short8*)&Ahi[BUF][off_st] = _h; *(short8*)&Alo[BUF][off_st] = _l;  \
        cvt8(B0, B1, _h, _l);                                                \
        *(short8*)&Bhi[BUF][off_st] = _h; *(short8*)&Blo[BUF][off_st] = _l;  \
    } while (0)

#define FRAG_MFMA(BUF) do {                                                  \
        short8 ah[2], al[2], bh[4], bl[4];                                   \
        _Pragma("unroll")                                                    \
        for (int i2 = 0; i2 < 2; ++i2) {                                     \
            const int aoff = ((wm >> 4) + i2) * 512 + rds;                   \
            ah[i2] = *(const short8*)&Ahi[BUF][aoff];                        \
            al[i2] = *(const short8*)&Alo[BUF][aoff];                        \
        }                                                                    \
        _Pragma("unroll")                                                    \
        for (int i2 = 0; i2 < 4; ++i2) {                                     \
            const int boff = ((wn >> 4) + i2) * 512 + rds;                   \
            bh[i2] = *(const short8*)&Bhi[BUF][boff];                        \
            bl[i2] = *(const short8*)&Blo[BUF][boff];                        \
        }                                                                    \
        _Pragma("unroll")                                                    \
        for (int mi = 0; mi < 2; ++mi)                                       \
            _Pragma("unroll")                                                \
            for (int nj = 0; nj < 4; ++nj) {                                 \
                acc[mi][nj] = __builtin_amdgcn_mfma_f32_16x16x32_bf16(ah[mi], bh[nj], acc[mi][nj], 0, 0, 0); \
                acc[mi][nj] = __builtin_amdgcn_mfma_f32_16x16x32_bf16(ah[mi], bl[nj], acc[mi][nj], 0, 0, 0); \
                acc[mi][nj] = __builtin_amdgcn_mfma_f32_16x16x32_bf16(al[mi], bh[nj], acc[mi][nj], 0, 0, 0); \
            }                                                                \
    } while (0)

    // Raw barrier: drains LDS ops (buffer handoff) but leaves the prefetch
    // global loads in flight (no vmcnt drain). Validated R2.
#define PIPE_BARRIER() asm volatile("s_waitcnt lgkmcnt(0)\n\ts_barrier" ::: "memory")

    // Two named prefetch register sets (X, Y) — rule #20, no runtime index.
    float4 ax0 = make_float4(0.f, 0.f, 0.f, 0.f), ax1 = ax0;
    float4 bx0, bx1;
    float4 ay0 = make_float4(0.f, 0.f, 0.f, 0.f), ay1 = ay0;
    float4 by0, by1;

    // --- prologue: tile0 -> buf0; tile1 -> regsX ---
    LOAD_SET(ax0, ax1, bx0, bx1, 0);
    CVT_STORE_SET(ax0, ax1, bx0, bx1, 0);
    LOAD_SET(ax0, ax1, bx0, bx1, TK);
    PIPE_BARRIER();   // buf0 ready; t1 loads stay in flight

    // --- main loop: 15 pairs (R2-validated schedule) ---
    int ke = 2 * TK;
#pragma unroll 1
    for (int i = 0; i < 15; ++i) {
        {   // even: compute buf0, load tile 2i+2 -> Y, stage X -> buf1
            LOAD_SET(ay0, ay1, by0, by1, ke);
            FRAG_MFMA(0);
            CVT_STORE_SET(ax0, ax1, bx0, bx1, 1);
            PIPE_BARRIER();
        }
        {   // odd: compute buf1, load tile 2i+3 -> X, stage Y -> buf0
            LOAD_SET(ax0, ax1, bx0, bx1, ke + TK);
            FRAG_MFMA(1);
            CVT_STORE_SET(ay0, ay1, by0, by1, 0);
            PIPE_BARRIER();
        }
        ke += 2 * TK;
    }
    // --- epilogue: tile30 in buf0, tile31 in regsX ---
    {
        FRAG_MFMA(0);
        CVT_STORE_SET(ax0, ax1, bx0, bx1, 1);
        PIPE_BARRIER();
    }
    {
        FRAG_MFMA(1);
    }

#undef LOAD_SET
#undef CVT_STORE_SET
#undef FRAG_MFMA
#undef PIPE_BARRIER

    // Epilogue: C/D layout col=lane&15, row=(lane>>4)*4+reg (validated).
    const int cl = lane & 15;
    const int qd = lane >> 4;
    float bv[4];
#pragma unroll
    for (int nj = 0; nj < 4; ++nj)
        bv[nj] = bias[e * D_OUT + n0 + wn + nj * 16 + cl];
#pragma unroll
    for (int mi = 0; mi < 2; ++mi) {
#pragma unroll
        for (int reg = 0; reg < 4; ++reg) {
            const int mloc = wm + mi * 16 + qd * 4 + reg;
            const int r = rows_s[mloc];
            if (r >= 0) {
                float* orow = out + (size_t)r * D_OUT + n0 + wn + cl;
#pragma unroll
                for (int nj = 0; nj < 4; ++nj)
                    orow[nj * 16] = acc[mi][nj][reg] + bv[nj];
            }
        }
    }
}

extern "C" void kernel_launch(void* const* d_in, const int* in_sizes, int n_in,
                              void* d_out, int out_size, void* d_ws, size_t ws_size,
                              hipStream_t stream) {
    const float* xs      = (const float*)d_in[0];
    const int*   mxs     = (const int*)d_in[1];
    const int*   actions = (const int*)d_in[2];
    const float* W       = (const float*)d_in[3];
    const float* bias    = (const float*)d_in[4];
    float* out = (float*)d_out;
    int*   ws  = (int*)d_ws;

    const int metaOff = BATCH * D_OUT;
    const int meta_mode = (out_size >= metaOff + 3 * BATCH) ? 2
                        : (out_size >= metaOff + 2 * BATCH) ? 1 : 0;

    group_meta_kernel<<<17, 256, 0, stream>>>(actions, mxs, ws, out, meta_mode);

    dim3 grid(D_OUT / TNX, MAX_TILES_128, 1);
    moe_gemm<<<grid, 512, 0, stream>>>(xs, W, bias, ws, out);
}